// Round 5
// baseline (1587.502 us; speedup 1.0000x reference)
//
#include <hip/hip_runtime.h>
#include <math.h>

#define Bb 16
#define Nn 2048
#define Dd 256
#define Cc 128
#define Kk 20
#define BIG_NEG -1.0e9f

// workspace layout (float offsets)
#define WS_EMIS   0
#define WS_MSC    (WS_EMIS + Bb*Nn*Cc)          // means * inv_var, bf16  [C][D]
#define WS_XQ     (WS_MSC + Cc*Dd)              // sum f^2*inv_var  [B*N]
#define WS_ECHAN  (WS_XQ + Bb*Nn)               // const - 0.5*mq   [C]
#define WS_T      (WS_ECHAN + Cc)               // exp(trans_lp)    [C][C]
#define WS_LEN    (WS_T + Cc*Cc)                // len_lp           [K][C]
#define WS_INIT   (WS_LEN + Kk*Cc)              // init_lp          [C]
#define WS_IVAR   (WS_INIT + Cc)                // 1/cov            [D]

typedef __attribute__((ext_vector_type(8))) short short8;
typedef __attribute__((ext_vector_type(4))) float float4v;
typedef __attribute__((ext_vector_type(8))) unsigned short u16x8;
typedef __attribute__((ext_vector_type(4))) unsigned short u16x4;
typedef __attribute__((ext_vector_type(2))) unsigned short u16x2;

__device__ __forceinline__ unsigned short f32_to_bf16(float x) {
  unsigned int u = __builtin_bit_cast(unsigned int, x);
  u = (u + 0x7FFFu + ((u >> 16) & 1u)) >> 16;
  return (unsigned short)u;
}

#define DPP_STEP(x, op, ctrl, rmask)                                          \
  do {                                                                        \
    int _yi = __builtin_amdgcn_update_dpp(                                    \
        __builtin_bit_cast(int, x), __builtin_bit_cast(int, x), ctrl, rmask,  \
        0xF, true);                                                           \
    x = op(x, __builtin_bit_cast(float, _yi));                                \
  } while (0)

__device__ __forceinline__ float dpp_add(float a, float b) { return a + b; }

__device__ __forceinline__ float wave_max64(float x) {
  DPP_STEP(x, fmaxf, 0xB1, 0xF);
  DPP_STEP(x, fmaxf, 0x4E, 0xF);
  DPP_STEP(x, fmaxf, 0x141, 0xF);
  DPP_STEP(x, fmaxf, 0x140, 0xF);
  DPP_STEP(x, fmaxf, 0x142, 0xA);
  DPP_STEP(x, fmaxf, 0x143, 0xC);
  return __builtin_bit_cast(float,
      __builtin_amdgcn_readlane(__builtin_bit_cast(int, x), 63));
}

__device__ __forceinline__ float wave_sum64(float x) {
  DPP_STEP(x, dpp_add, 0xB1, 0xF);
  DPP_STEP(x, dpp_add, 0x4E, 0xF);
  DPP_STEP(x, dpp_add, 0x141, 0xF);
  DPP_STEP(x, dpp_add, 0x140, 0xF);
  DPP_STEP(x, dpp_add, 0x142, 0xA);
  DPP_STEP(x, dpp_add, 0x143, 0xC);
  return __builtin_bit_cast(float,
      __builtin_amdgcn_readlane(__builtin_bit_cast(int, x), 63));
}

// raw barrier: LDS-ordering only; global prefetch loads float across (no vmcnt drain)
#define WAVE_BARRIER() asm volatile("s_waitcnt lgkmcnt(0)\n\ts_barrier" ::: "memory")

// wv from the p-fragments (all 128 bf16, >=0 -> monotone as u16). Both waves compute
// the IDENTICAL value from identical data -> no LDS exchange needed for the scale.
__device__ __forceinline__ float frag_max_to_f32(short8 a, short8 b, short8 c, short8 d) {
  u16x8 ua = __builtin_bit_cast(u16x8, a), ub = __builtin_bit_cast(u16x8, b);
  u16x8 uc = __builtin_bit_cast(u16x8, c), ud = __builtin_bit_cast(u16x8, d);
  u16x8 m8 = __builtin_elementwise_max(__builtin_elementwise_max(ua, ub),
                                       __builtin_elementwise_max(uc, ud));
  u16x4 lo4 = __builtin_shufflevector(m8, m8, 0, 1, 2, 3);
  u16x4 hi4 = __builtin_shufflevector(m8, m8, 4, 5, 6, 7);
  u16x4 m4 = __builtin_elementwise_max(lo4, hi4);
  u16x2 lo2 = __builtin_shufflevector(m4, m4, 0, 1);
  u16x2 hi2 = __builtin_shufflevector(m4, m4, 2, 3);
  u16x2 m2 = __builtin_elementwise_max(lo2, hi2);
  unsigned mm = (unsigned)m2[0];
  unsigned m1 = (unsigned)m2[1];
  mm = mm > m1 ? mm : m1;
  // cross-g reduce (values uniform within each 16-lane row): bcast15, bcast31
  {
    int y = __builtin_amdgcn_update_dpp((int)mm, (int)mm, 0x142, 0xA, 0xF, true);
    unsigned uy = (unsigned)y; mm = mm > uy ? mm : uy;
    y = __builtin_amdgcn_update_dpp((int)mm, (int)mm, 0x143, 0xC, 0xF, true);
    uy = (unsigned)y; mm = mm > uy ? mm : uy;
  }
  unsigned full = (unsigned)__builtin_amdgcn_readlane((int)mm, 63);
  return __builtin_bit_cast(float, full << 16);
}

// ---------------- small precompute (1 block, 256 threads) ----------------
__global__ void prep_kernel(const float* __restrict__ means,
                            const float* __restrict__ cov,
                            const float* __restrict__ tl,
                            const float* __restrict__ il,
                            const float* __restrict__ plr,
                            float* __restrict__ ws) {
  __shared__ float s_iv[Dd];
  __shared__ float s_red[4];
  __shared__ float s_tlse[Cc];
  int tid = threadIdx.x;

  float cv = cov[tid];
  float iv = 1.0f / cv;
  s_iv[tid] = iv;
  ws[WS_IVAR + tid] = iv;
  float lg = __logf(cv);
  #pragma unroll
  for (int off = 1; off < 64; off <<= 1) lg += __shfl_xor(lg, off, 64);
  if ((tid & 63) == 0) s_red[tid >> 6] = lg;
  __syncthreads();
  float logdet = s_red[0] + s_red[1] + s_red[2] + s_red[3];
  float cconst = -0.5f * ((float)Dd * 1.8378770664093453f + logdet);

  unsigned short* mscb = (unsigned short*)(ws + WS_MSC);
  for (int idx = tid; idx < Cc * Dd; idx += 256) {
    int d = idx & (Dd - 1);
    mscb[idx] = f32_to_bf16(means[idx] * s_iv[d]);
  }
  if (tid < Cc) {
    float acc = 0.0f;
    for (int d = 0; d < Dd; d++) {
      float m = means[tid * Dd + d];
      acc = fmaf(m * m, s_iv[d], acc);
    }
    ws[WS_ECHAN + tid] = cconst - 0.5f * acc;
  }
  for (int idx = tid; idx < Kk * Cc; idx += 256) {
    int L = idx / Cc + 1;
    int c = idx & (Cc - 1);
    float r = plr[c];
    ws[WS_LEN + idx] = (float)L * r - __expf(r) - lgammaf((float)(L + 1));
  }

  __syncthreads();
  float x = (tid < Cc) ? il[tid] : -INFINITY;
  float mx = x;
  #pragma unroll
  for (int off = 1; off < 64; off <<= 1) mx = fmaxf(mx, __shfl_xor(mx, off, 64));
  if ((tid & 63) == 0) s_red[tid >> 6] = mx;
  __syncthreads();
  float M = fmaxf(s_red[0], s_red[1]);
  float se = (tid < Cc) ? __expf(x - M) : 0.0f;
  #pragma unroll
  for (int off = 1; off < 64; off <<= 1) se += __shfl_xor(se, off, 64);
  __syncthreads();
  if ((tid & 63) == 0) s_red[tid >> 6] = se;
  __syncthreads();
  float lse = M + __logf(s_red[0] + s_red[1]);
  if (tid < Cc) ws[WS_INIT + tid] = x - lse;

  if (tid < Cc) {
    int j = tid;
    float m2 = -INFINITY;
    for (int i = 0; i < Cc; i++) if (i != j) m2 = fmaxf(m2, tl[i * Cc + j]);
    float s2 = 0.0f;
    for (int i = 0; i < Cc; i++) if (i != j) s2 += __expf(tl[i * Cc + j] - m2);
    s_tlse[j] = m2 + __logf(s2);
  }
  __syncthreads();
  for (int idx = tid; idx < Cc * Cc; idx += 256) {
    int i = idx / Cc;
    int j = idx & (Cc - 1);
    ws[WS_T + idx] = (i == j) ? 0.0f : __expf(tl[idx] - s_tlse[j]);
  }
}

// ---------------- xq[b,n] = sum_d f^2 * inv_var (one wave per position) ----------------
__global__ void xq_kernel(const float* __restrict__ f, float* __restrict__ ws) {
  int pos = blockIdx.x * 4 + (threadIdx.x >> 6);
  int lane = threadIdx.x & 63;
  const float4 fv = *(const float4*)&f[(size_t)pos * Dd + lane * 4];
  const float4 vv = *(const float4*)&ws[WS_IVAR + lane * 4];
  float a = fv.x * fv.x * vv.x + fv.y * fv.y * vv.y +
            fv.z * fv.z * vv.z + fv.w * fv.w * vv.w;
  #pragma unroll
  for (int off = 1; off < 64; off <<= 1) a += __shfl_xor(a, off, 64);
  if (lane == 0) ws[WS_XQ + pos] = a;
}

// ---------------- emission via MFMA: 32n x 128c per block, 4 waves ----------------
__launch_bounds__(256)
__global__ void emis_mfma_kernel(const float* __restrict__ f, float* __restrict__ ws) {
  const unsigned short* msc = (const unsigned short*)(ws + WS_MSC);
  float* emis = ws + WS_EMIS;
  int tid = threadIdx.x;
  int w = tid >> 6, lane = tid & 63, g = lane >> 4, l16 = lane & 15;
  int b = blockIdx.x >> 6;
  int n0 = (blockIdx.x & 63) << 5;
  int c0 = w << 5;

  const float* fbase = f + (size_t)(b * Nn + n0) * Dd;
  float4v acc[2][2];
  #pragma unroll
  for (int rt = 0; rt < 2; rt++)
    #pragma unroll
    for (int ct = 0; ct < 2; ct++) acc[rt][ct] = (float4v){0.f, 0.f, 0.f, 0.f};

  #pragma unroll
  for (int k0 = 0; k0 < Dd; k0 += 32) {
    int kk = k0 + g * 8;
    short8 afr[2], bfr[2];
    #pragma unroll
    for (int rt = 0; rt < 2; rt++) {
      const float* src = fbase + (size_t)(rt * 16 + l16) * Dd + kk;
      float4 v0 = *(const float4*)src;
      float4 v1 = *(const float4*)(src + 4);
      short8 fr;
      fr[0] = (short)f32_to_bf16(v0.x); fr[1] = (short)f32_to_bf16(v0.y);
      fr[2] = (short)f32_to_bf16(v0.z); fr[3] = (short)f32_to_bf16(v0.w);
      fr[4] = (short)f32_to_bf16(v1.x); fr[5] = (short)f32_to_bf16(v1.y);
      fr[6] = (short)f32_to_bf16(v1.z); fr[7] = (short)f32_to_bf16(v1.w);
      afr[rt] = fr;
    }
    #pragma unroll
    for (int ct = 0; ct < 2; ct++)
      bfr[ct] = *(const short8*)&msc[(size_t)(c0 + ct * 16 + l16) * Dd + kk];
    #pragma unroll
    for (int rt = 0; rt < 2; rt++)
      #pragma unroll
      for (int ct = 0; ct < 2; ct++)
        acc[rt][ct] = __builtin_amdgcn_mfma_f32_16x16x32_bf16(afr[rt], bfr[ct], acc[rt][ct], 0, 0, 0);
  }

  #pragma unroll
  for (int rt = 0; rt < 2; rt++) {
    #pragma unroll
    for (int ct = 0; ct < 2; ct++) {
      int cc = c0 + ct * 16 + l16;
      float ec = ws[WS_ECHAN + cc];
      #pragma unroll
      for (int r = 0; r < 4; r++) {
        int row = rt * 16 + g * 4 + r;
        int nn = n0 + row;
        emis[(size_t)(b * Nn + nn) * Cc + cc] =
            ec - 0.5f * ws[WS_XQ + b * Nn + nn] + acc[rt][ct][r];
      }
    }
  }
}

// ---------------- semi-Markov scan: 2 waves/batch, minimal-stage chain ----------------
// Invariants (round-4 verified algebra, r-placement moved one step later):
//   q = unnormalized u_t = M v_t; state scale A_t = me_t + log max(V_{t-1})  (delayed
//   deadbeat, FIR -> stable).  eesc_t = exp(e_t - me_t) * r_{t-1}  (r_{t-1}=rcp(wv_{t-1}))
//   is BOTH the v-multiplier and the E-window shift factor.  dla_t = me_t + log wv_{t-1}.
// Chain per step:  S=fma(q,elen0,Stail) -> v=S*eesc -> trunc-bf16 -> ds_write ->
//   lgkm -> s_barrier (raw: NO vmcnt drain) -> ds_read x4 -> MFMA (2+2) -> add/select -> q.
// Off-chain: wv from fragments (pk_max_u16 tree, identical in both waves -> no exchange),
//   eesc_next, E-shift, Stail tree, Kahan accounting, me exchange (parity LDS), 1-2
//   emission prefetch loads (float across raw barriers, counted vmcnt at use).
__launch_bounds__(128, 1)
__global__ void scan_kernel(const int* __restrict__ lengths,
                            const float* __restrict__ ws,
                            float* __restrict__ out) {
  __shared__ __align__(16) unsigned short p_lds[2][Cc];  // ping-pong, unnormalized bf16
  __shared__ float lds_men[2][2][8];    // [group parity][wave][slot] emission row max
  __shared__ float lds_out[2][2];       // [{M, ps}][wave]

  int tid = threadIdx.x;
  int w = tid >> 6;
  int lane = tid & 63;
  int g = lane >> 4;
  int l15 = lane & 15;
  int c = w * 64 + lane;
  int b = blockIdx.x;
  int len_b = lengths[b];
  const float* emis = ws + WS_EMIS + (size_t)b * Nn * Cc;

  // T fragments (MFMA B operand), this wave's 4 tiles x 4 k-chunks:
  // lane holds T[(w*4+nt)*16 + l15][kc*32 + g*8 + j]
  short8 Tf[4][4];
  {
    const float* T = ws + WS_T;
    #pragma unroll
    for (int nt = 0; nt < 4; nt++)
      #pragma unroll
      for (int kc = 0; kc < 4; kc++) {
        const float* src = &T[(size_t)((w * 4 + nt) * 16 + l15) * Cc + kc * 32 + g * 8];
        short8 fr;
        #pragma unroll
        for (int j = 0; j < 8; j++) fr[j] = (short)f32_to_bf16(src[j]);
        Tf[nt][kc] = fr;
      }
  }

  float elen[Kk];
  #pragma unroll
  for (int k = 0; k < Kk; k++) elen[k] = __expf(ws[WS_LEN + k * Cc + c]);
  float elen0 = elen[0];

  float E[Kk - 1];
  #pragma unroll
  for (int s = 0; s < Kk - 1; s++) E[s] = 0.0f;

  float q = __expf(ws[WS_INIT + c]);   // u_0, scale A_0 = 0
  float Stail = 0.0f;
  float cum = 0.0f;                    // exact-order cumsum (matches reference)
  float Dlt = 0.0f, dcomp = 0.0f;      // Kahan Delta = A_{t-1} - cum[t-1]
  float r = 1.0f;                      // rcp(wv_{t-1}); r_0 = 1
  float lwv = 0.0f;                    // log wv_{t-1}

  // emission prefetch: e[i] = row (t-1) for step t = tg+i
  float e[8], en[8];
  #pragma unroll
  for (int j = 0; j < 8; j++) e[j] = emis[(size_t)j * Cc + c];
  #pragma unroll
  for (int j = 0; j < 8; j++) {
    float m = wave_max64(e[j]);
    if (lane == 0) lds_men[0][w][j] = m;
  }
  WAVE_BARRIER();
  float eesc = __expf(e[0] - fmaxf(lds_men[0][0][0], lds_men[0][1][0]));  // * r_0=1

  bool done = false;
  for (int tg = 1; tg <= Nn && !done; tg += 8) {
    int gp = ((tg - 1) >> 3) & 1;      // current group's me buffer parity
    #pragma unroll
    for (int i = 0; i < 8; i++) {
      int t = tg + i;
      int buf = t & 1;
      bool fin = (t == len_b);
      float ecur = e[i];
      float S = fmaf(q, elen0, Stail);
      float a = 0.0f;

      // ---- pre-barrier: S -> v -> trunc -> ds_write (shortest possible chain) ----
      if (fin) {
        a = (cum + ecur) + Dlt + __logf(fmaxf(S, 1e-37f));
        float Mw = wave_max64(a);
        if (lane == 0) lds_out[0][w] = Mw;
      } else {
        float v = S * eesc;                      // unnormalized (bf16 = scale-free)
        p_lds[buf][c] =
            (unsigned short)(__builtin_bit_cast(unsigned int, v) >> 16);
      }
      WAVE_BARRIER();                            // lgkm-only drain

      // ---- post-barrier ----
      if (fin) {
        float Mb = fmaxf(lds_out[0][0], lds_out[0][1]);
        float ps = wave_sum64(__expf(a - Mb));
        if (lane == 0) lds_out[1][w] = ps;
        WAVE_BARRIER();
        if (tid == 0) out[b] = Mb + __logf(lds_out[1][0] + lds_out[1][1]);
        done = true;
        break;
      }

      // p-fragment LDS reads (issue immediately)
      short8 pa0 = *(const short8*)&p_lds[buf][g * 8];
      short8 pa1 = *(const short8*)&p_lds[buf][32 + g * 8];
      short8 pa2 = *(const short8*)&p_lds[buf][64 + g * 8];
      short8 pa3 = *(const short8*)&p_lds[buf][96 + g * 8];

      // spread emission prefetch (floats across raw barriers; used >=2 steps later)
      if (i == 0) {
        int r0 = tg + 7;  if (r0 > Nn - 1) r0 = Nn - 1;
        int r1 = tg + 8;  if (r1 > Nn - 1) r1 = Nn - 1;
        int r2 = tg + 9;  if (r2 > Nn - 1) r2 = Nn - 1;
        en[0] = emis[(size_t)r0 * Cc + c];
        en[1] = emis[(size_t)r1 * Cc + c];
        en[2] = emis[(size_t)r2 * Cc + c];
      } else if (i <= 5) {
        int rr = tg + 9 + i; if (rr > Nn - 1) rr = Nn - 1;
        en[i + 2] = emis[(size_t)rr * Cc + c];
      }

      // shared scale from the fragments (identical in both waves, no LDS exchange)
      float wv = fmaxf(frag_max_to_f32(pa0, pa1, pa2, pa3), 1.0e-30f);

      // matvec: this wave's 4 tiles, 2+2 k-chunk chains
      float4v z = {0.0f, 0.0f, 0.0f, 0.0f};
      float qv[4];
      #pragma unroll
      for (int nt = 0; nt < 4; nt++) {
        float4v x = __builtin_amdgcn_mfma_f32_16x16x32_bf16(pa1, Tf[nt][1],
                      __builtin_amdgcn_mfma_f32_16x16x32_bf16(pa0, Tf[nt][0], z, 0, 0, 0),
                      0, 0, 0);
        float4v y = __builtin_amdgcn_mfma_f32_16x16x32_bf16(pa3, Tf[nt][3],
                      __builtin_amdgcn_mfma_f32_16x16x32_bf16(pa2, Tf[nt][2], z, 0, 0, 0),
                      0, 0, 0);
        qv[nt] = x[0] + y[0];
      }

      // off-chain: E-window shift with eesc_t (uses OLD q = u_{t-1})
      #pragma unroll
      for (int s = Kk - 2; s >= 1; s--) E[s] = E[s - 1] * eesc;
      E[0] = q * eesc;

      float s0 = E[0] * elen[1];
      float s1 = E[1] * elen[2];
      float s2 = E[2] * elen[3];
      float s3 = E[3] * elen[4];
      s0 = fmaf(E[4], elen[5], s0);   s1 = fmaf(E[5], elen[6], s1);
      s2 = fmaf(E[6], elen[7], s2);   s3 = fmaf(E[7], elen[8], s3);
      s0 = fmaf(E[8], elen[9], s0);   s1 = fmaf(E[9], elen[10], s1);
      s2 = fmaf(E[10], elen[11], s2); s3 = fmaf(E[11], elen[12], s3);
      s0 = fmaf(E[12], elen[13], s0); s1 = fmaf(E[13], elen[14], s1);
      s2 = fmaf(E[14], elen[15], s2); s3 = fmaf(E[15], elen[16], s3);
      s0 = fmaf(E[16], elen[17], s0); s1 = fmaf(E[17], elen[18], s1);
      s2 = fmaf(E[18], elen[19], s2);
      Stail = (s0 + s1) + (s2 + s3);

      // accounting: dla_t = me_t + log wv_{t-1} (lagged, consistent with eesc)
      float meC = fmaxf(lds_men[gp][0][i], lds_men[gp][1][i]);
      float dla = meC + lwv;
      {
        float dd = dla - ecur;
        float yk = dd - dcomp;
        float t2 = Dlt + yk;
        dcomp = (t2 - Dlt) - yk;
        Dlt = t2;
      }
      cum += ecur;

      // advance the deferred scale
      r = __builtin_amdgcn_rcpf(wv);
      lwv = __logf(wv);

      // next-group me production (own-wave max -> LDS buf gp^1)
      if (i >= 2) {
        float m = wave_max64(en[i - 2]);
        if (lane == 0) lds_men[gp ^ 1][w][i - 2] = m;
      }
      if (i == 6) {
        float m = wave_max64(en[6]);
        if (lane == 0) lds_men[gp ^ 1][w][6] = m;
      }
      if (i == 7) {
        float m = wave_max64(en[7]);
        if (lane == 0) lds_men[gp ^ 1][w][7] = m;
      }

      // eesc for next step (me from parity buffer; includes r_t)
      if (i < 7) {
        float meN = fmaxf(lds_men[gp][0][i + 1], lds_men[gp][1][i + 1]);
        eesc = __expf(e[i + 1] - meN) * r;
      }

      // in-lane select: lane's channel c = w*64 + g*16 + l15 -> tile g, col l15
      float qs01 = (g & 1) ? qv[1] : qv[0];
      float qs23 = (g & 1) ? qv[3] : qv[2];
      float qs = (g & 2) ? qs23 : qs01;
      q = qs;                           // u_t, unnormalized (r folded into eesc_{t+1})
    }
    if (!done) {
      #pragma unroll
      for (int j = 0; j < 8; j++) e[j] = en[j];
      int gp = ((tg - 1) >> 3) & 1;
      float me0 = fmaxf(lds_men[gp ^ 1][0][0], lds_men[gp ^ 1][1][0]);
      eesc = __expf(e[0] - me0) * r;
    }
  }
}

extern "C" void kernel_launch(void* const* d_in, const int* in_sizes, int n_in,
                              void* d_out, int out_size, void* d_ws, size_t ws_size,
                              hipStream_t stream) {
  const float* features = (const float*)d_in[0];
  const int* lengths = (const int*)d_in[1];
  const float* means = (const float*)d_in[2];
  const float* cov = (const float*)d_in[3];
  const float* tl = (const float*)d_in[4];
  const float* il = (const float*)d_in[5];
  const float* plr = (const float*)d_in[6];
  float* out = (float*)d_out;
  float* ws = (float*)d_ws;

  prep_kernel<<<1, 256, 0, stream>>>(means, cov, tl, il, plr, ws);
  xq_kernel<<<(Bb * Nn) / 4, 256, 0, stream>>>(features, ws);
  emis_mfma_kernel<<<Bb * (Nn / 32), 256, 0, stream>>>(features, ws);
  scan_kernel<<<Bb, 128, 0, stream>>>(lengths, ws, out);
}